// Round 2
// baseline (409.590 us; speedup 1.0000x reference)
//
#include <hip/hip_runtime.h>

// RNN LM forward, two-phase, MI355X (gfx950).
// B=1024, T=256, V=256, H=32.
//
// Phase 1 (rnn_recur): one wave per batch. h_j lives in lane j's register;
//   cross-lane h broadcast via v_readlane (no LDS, no barriers). Lanes 32-63
//   mirror lanes 0-31 so the hot loop has no divergence. Embedding for step
//   t+1 prefetched during step t. hs[b][t][j] (32 MiB) written to d_ws.
// Phase 2 (rnn_proj): streaming projection. Thread owns v=tid, W_hq column
//   in 32 VGPRs; 32-row h chunks staged in LDS (conflict-free broadcast
//   reads); coalesced dword stores of the 256 MiB output.
//
// Roofline: output write 256 MiB -> ~42 us; projection VALU 27 us (hidden);
// recurrence ~20 us latency-bound serial chain.

#define B_SZ 1024
#define T_SZ 256
#define V_SZ 256
#define H_SZ 32

__device__ __forceinline__ float lane_f(float v, int i) {
    return __int_as_float(__builtin_amdgcn_readlane(__float_as_int(v), i));
}

__device__ __forceinline__ float fast_tanh(float x) {
    // tanh(x) = (e^{2x}-1)/(e^{2x}+1); |x| < ~0.5 here (sigma=0.01 weights)
    float z = __expf(2.0f * x);
    return __fdividef(z - 1.0f, z + 1.0f);
}

// ---------------- Phase 1: recurrence -> hs[b][t][j] ----------------
__global__ __launch_bounds__(256, 2) void rnn_recur(
    const int*   __restrict__ X,      // [B, T]
    const float* __restrict__ W_xh,   // [V, H]
    const float* __restrict__ W_hh,   // [H, H]
    const float* __restrict__ b_h,    // [H]
    float*       __restrict__ hs)     // [B, T, H]
{
    const int lane = threadIdx.x & 63;
    const int wave = threadIdx.x >> 6;
    const int b    = blockIdx.x * 4 + wave;   // grid = 256 blocks
    const int j    = lane & 31;               // lanes 32-63 mirror 0-31

    // W_hh column j in registers (4 KiB table, L1-cached after first touch)
    float whh[H_SZ];
    #pragma unroll
    for (int i = 0; i < H_SZ; ++i) whh[i] = W_hh[i * H_SZ + j];
    const float bh = b_h[j];

    const int* xb = X + b * T_SZ;
    float*     hb = hs + (size_t)b * T_SZ * H_SZ;

    float h = 0.0f;
    float e = W_xh[xb[0] * H_SZ + j];   // prefetched embedding for step 0

    for (int t = 0; t < T_SZ; ++t) {
        const float e_cur = e;
        if (t + 1 < T_SZ) e = W_xh[xb[t + 1] * H_SZ + j];  // prefetch next

        float a0 = e_cur + bh, a1 = 0.0f, a2 = 0.0f, a3 = 0.0f;
        #pragma unroll
        for (int i = 0; i < H_SZ; i += 4) {
            a0 += lane_f(h, i + 0) * whh[i + 0];
            a1 += lane_f(h, i + 1) * whh[i + 1];
            a2 += lane_f(h, i + 2) * whh[i + 2];
            a3 += lane_f(h, i + 3) * whh[i + 3];
        }
        h = fast_tanh((a0 + a1) + (a2 + a3));

        if (lane < H_SZ) hb[t * H_SZ + j] = h;  // 128 B contiguous per wave
    }
}

// ---------------- Phase 2: projection -> out[b][t][v] ----------------
__global__ __launch_bounds__(256, 4) void rnn_proj(
    const float* __restrict__ hs,     // [B*T, H] rows
    const float* __restrict__ W_hq,   // [H, V]
    const float* __restrict__ b_q,    // [V]
    float*       __restrict__ out)    // [B*T, V] rows
{
    __shared__ float sh[32 * H_SZ];   // 32-row chunk of h (4 KiB)

    const int tid = threadIdx.x;      // = vocab slot v

    float whq[H_SZ];
    #pragma unroll
    for (int jj = 0; jj < H_SZ; ++jj) whq[jj] = W_hq[jj * V_SZ + tid];
    const float bq = b_q[tid];

    const size_t row0 = (size_t)blockIdx.x * 128;  // grid = 2048 blocks

    for (int c = 0; c < 4; ++c) {
        const size_t rbase = row0 + (size_t)c * 32;
        // stage 32 rows (1024 floats): one float4 per thread, coalesced
        ((float4*)sh)[tid] = ((const float4*)(hs + rbase * H_SZ))[tid];
        __syncthreads();

        #pragma unroll 4
        for (int r = 0; r < 32; ++r) {
            const float4* hv = (const float4*)(sh + r * H_SZ);
            float acc = bq;
            #pragma unroll
            for (int q = 0; q < H_SZ / 4; ++q) {
                const float4 h4 = hv[q];   // broadcast: all lanes same addr
                acc += h4.x * whq[4 * q + 0];
                acc += h4.y * whq[4 * q + 1];
                acc += h4.z * whq[4 * q + 2];
                acc += h4.w * whq[4 * q + 3];
            }
            out[(rbase + r) * V_SZ + tid] = acc;  // coalesced stream
        }
        __syncthreads();
    }
}

// ---------------- Fallback: R0 fused kernel (if ws too small) ----------------
__global__ __launch_bounds__(256, 4) void rnnlm_fused(
    const int* __restrict__ X, const float* __restrict__ W_xh,
    const float* __restrict__ W_hh, const float* __restrict__ b_h,
    const float* __restrict__ W_hq, const float* __restrict__ b_q,
    float* __restrict__ out)
{
    __shared__ float s_wxh[V_SZ * H_SZ];
    __shared__ int   s_tok[T_SZ];
    __shared__ float s_h[2][H_SZ];

    const int tid = threadIdx.x;
    const int b   = blockIdx.x;

    #pragma unroll
    for (int i = 0; i < (V_SZ * H_SZ) / 256; ++i)
        s_wxh[i * 256 + tid] = W_xh[i * 256 + tid];
    s_tok[tid] = X[b * T_SZ + tid];

    float whq[H_SZ];
    #pragma unroll
    for (int j = 0; j < H_SZ; ++j) whq[j] = W_hq[j * V_SZ + tid];
    const float bq = b_q[tid];

    float whh[H_SZ];
    float bh = 0.0f;
    if (tid < H_SZ) {
        #pragma unroll
        for (int i = 0; i < H_SZ; ++i) whh[i] = W_hh[i * H_SZ + tid];
        bh = b_h[tid];
        s_h[1][tid] = 0.0f;
    }
    __syncthreads();

    float* outp = out + (size_t)b * T_SZ * V_SZ + tid;

    for (int t = 0; t < T_SZ; ++t) {
        const int cur = t & 1, prv = cur ^ 1;
        if (tid < H_SZ) {
            const int tok = s_tok[t];
            float a0 = s_wxh[tok * H_SZ + tid] + bh;
            float a1 = 0.0f, a2 = 0.0f, a3 = 0.0f;
            #pragma unroll
            for (int i = 0; i < H_SZ; i += 4) {
                a0 += s_h[prv][i + 0] * whh[i + 0];
                a1 += s_h[prv][i + 1] * whh[i + 1];
                a2 += s_h[prv][i + 2] * whh[i + 2];
                a3 += s_h[prv][i + 3] * whh[i + 3];
            }
            s_h[cur][tid] = tanhf((a0 + a1) + (a2 + a3));
        }
        __syncthreads();
        float acc = bq;
        const float4* hv = (const float4*)s_h[cur];
        #pragma unroll
        for (int q = 0; q < H_SZ / 4; ++q) {
            const float4 h4 = hv[q];
            acc += h4.x * whq[4 * q + 0];
            acc += h4.y * whq[4 * q + 1];
            acc += h4.z * whq[4 * q + 2];
            acc += h4.w * whq[4 * q + 3];
        }
        outp[t * V_SZ] = acc;
    }
}

extern "C" void kernel_launch(void* const* d_in, const int* in_sizes, int n_in,
                              void* d_out, int out_size, void* d_ws, size_t ws_size,
                              hipStream_t stream) {
    const int*   X    = (const int*)d_in[0];
    const float* W_xh = (const float*)d_in[1];
    const float* W_hh = (const float*)d_in[2];
    const float* b_h  = (const float*)d_in[3];
    const float* W_hq = (const float*)d_in[4];
    const float* b_q  = (const float*)d_in[5];
    float* out = (float*)d_out;

    const size_t hs_bytes = (size_t)B_SZ * T_SZ * H_SZ * sizeof(float); // 32 MiB

    if (ws_size >= hs_bytes) {
        float* hs = (float*)d_ws;
        rnn_recur<<<dim3(B_SZ / 4), dim3(256), 0, stream>>>(X, W_xh, W_hh, b_h, hs);
        rnn_proj<<<dim3((B_SZ * T_SZ) / 128), dim3(256), 0, stream>>>(hs, W_hq, b_q, out);
    } else {
        rnnlm_fused<<<dim3(B_SZ), dim3(256), 0, stream>>>(X, W_xh, W_hh, b_h, W_hq, b_q, out);
    }
}